// Round 1
// baseline (447.860 us; speedup 1.0000x reference)
//
#include <hip/hip_runtime.h>
#include <math.h>

#define BATCH 16
#define SEQ   2048
#define HID   128
#define DIM   64

// ---------------------------------------------------------------------------
// Kernel 0: wvf[h] = sum_d Wv[h][d] * Wf[d]   (collapses V@Wf into xp @ wvf)
// ---------------------------------------------------------------------------
__global__ void k_wvf(const float* __restrict__ Wv, const float* __restrict__ Wf,
                      float* __restrict__ wvf) {
    int h = threadIdx.x;
    if (h < HID) {
        float s = 0.f;
        #pragma unroll 8
        for (int d = 0; d < DIM; ++d) s += Wv[h * DIM + d] * Wf[d];
        wvf[h] = s;
    }
}

// ---------------------------------------------------------------------------
// Kernel 1: xp = x + PE;  Q = xp@Wq * 1/sqrt(D);  K = xp@Wk;  vf = xp@wvf
// 16 rows per block, 256 threads: thread (r=tid>>4, c=tid&15) computes
// Q/K[row r][d = 4c..4c+3].
// ---------------------------------------------------------------------------
#define ROWS 16
__global__ __launch_bounds__(256) void k_qkv(
    const float* __restrict__ x, const float* __restrict__ Wq,
    const float* __restrict__ Wk, const float* __restrict__ wvf,
    float* __restrict__ Qb, float* __restrict__ Kb, float* __restrict__ vf)
{
    __shared__ float xs[ROWS][HID];      // 8 KB
    __shared__ float wqs[HID * DIM];     // 32 KB
    __shared__ float wks[HID * DIM];     // 32 KB
    __shared__ float vred[ROWS][16];

    const int tid = threadIdx.x;

    // stage Wq, Wk
    {
        const float4* Wq4 = (const float4*)Wq;
        const float4* Wk4 = (const float4*)Wk;
        float4* wqs4 = (float4*)wqs;
        float4* wks4 = (float4*)wks;
        for (int i = tid; i < HID * DIM / 4; i += 256) {
            wqs4[i] = Wq4[i];
            wks4[i] = Wk4[i];
        }
    }

    // stage x rows + positional encoding
    {
        const float c0 = 9.2103403719761836f / 128.0f;  // ln(10000)/HID
        const float4* x4 = (const float4*)x;
        const int pos_base = (blockIdx.x & (SEQ / ROWS - 1)) * ROWS;
        for (int it = tid; it < ROWS * HID / 4; it += 256) {
            int r  = it >> 5;            // HID/4 = 32 float4 per row
            int h0 = (it & 31) << 2;
            float4 v = x4[(size_t)blockIdx.x * (ROWS * HID / 4) + it];
            float pos = (float)(pos_base + r);
            float vv[4] = {v.x, v.y, v.z, v.w};
            #pragma unroll
            for (int j = 0; j < 4; ++j) {
                int h = h0 + j;
                float ang = pos * expf(-(float)(h & ~1) * c0);
                float pe  = (h & 1) ? cosf(ang) : sinf(ang);
                vv[j] += pe;
            }
            float4 o = {vv[0], vv[1], vv[2], vv[3]};
            *(float4*)&xs[r][h0] = o;
        }
    }
    __syncthreads();

    const int r = tid >> 4;
    const int c = tid & 15;

    float qa[4] = {0.f, 0.f, 0.f, 0.f};
    float ka[4] = {0.f, 0.f, 0.f, 0.f};
    #pragma unroll 4
    for (int h = 0; h < HID; ++h) {
        float xv = xs[r][h];
        float4 wq4 = *(const float4*)&wqs[h * DIM + c * 4];
        float4 wk4 = *(const float4*)&wks[h * DIM + c * 4];
        qa[0] += xv * wq4.x; qa[1] += xv * wq4.y; qa[2] += xv * wq4.z; qa[3] += xv * wq4.w;
        ka[0] += xv * wk4.x; ka[1] += xv * wk4.y; ka[2] += xv * wk4.z; ka[3] += xv * wk4.w;
    }

    const size_t row = (size_t)blockIdx.x * ROWS + r;
    const float qscale = 0.125f;  // 1/sqrt(64)
    float4 qo = {qa[0] * qscale, qa[1] * qscale, qa[2] * qscale, qa[3] * qscale};
    float4 ko = {ka[0], ka[1], ka[2], ka[3]};
    *(float4*)&Qb[row * DIM + c * 4] = qo;
    *(float4*)&Kb[row * DIM + c * 4] = ko;

    // vf = xp . wvf (per row)
    float p = 0.f;
    #pragma unroll
    for (int j = 0; j < 8; ++j) p += xs[r][c * 8 + j] * wvf[c * 8 + j];
    vred[r][c] = p;
    __syncthreads();
    if (c == 0) {
        float s = 0.f;
        #pragma unroll
        for (int j = 0; j < 16; ++j) s += vred[r][j];
        vf[row] = s;
    }
}

// ---------------------------------------------------------------------------
// Kernel 2: column stats.  Block owns (b, 64 k-columns); iterates q-tiles of
// 64, keeping running m[k], l[k] (softmax over q for each column k).
// scores = Q(prescaled) . K
// ---------------------------------------------------------------------------
__global__ __launch_bounds__(256) void k_stats(
    const float* __restrict__ Qb, const float* __restrict__ Kb,
    float* __restrict__ mb, float* __restrict__ lb)
{
    const int b  = blockIdx.y;
    const int kt = blockIdx.x;   // k tile, 0..31
    __shared__ float Kt[DIM][64];   // [h][k col]
    __shared__ float Qs[DIM][64];   // [h][q row]
    __shared__ float red[16][64];
    __shared__ float colm[64], coll[64];

    const int tid = threadIdx.x;
    const int ty = tid >> 4, tx = tid & 15;

    // stage K tile transposed
    {
        const float4* Kb4 = (const float4*)(Kb + ((size_t)b * SEQ + kt * 64) * DIM);
        for (int i = tid; i < 64 * 16; i += 256) {
            int rw = i >> 4;
            int h4 = (i & 15) << 2;
            float4 v = Kb4[i];
            Kt[h4 + 0][rw] = v.x; Kt[h4 + 1][rw] = v.y;
            Kt[h4 + 2][rw] = v.z; Kt[h4 + 3][rw] = v.w;
        }
    }
    if (tid < 64) { colm[tid] = -3.0e38f; coll[tid] = 0.f; }
    __syncthreads();

    for (int qt = 0; qt < SEQ / 64; ++qt) {
        // stage Q tile transposed
        {
            const float4* Qb4 = (const float4*)(Qb + ((size_t)b * SEQ + qt * 64) * DIM);
            for (int i = tid; i < 64 * 16; i += 256) {
                int rw = i >> 4;
                int h4 = (i & 15) << 2;
                float4 v = Qb4[i];
                Qs[h4 + 0][rw] = v.x; Qs[h4 + 1][rw] = v.y;
                Qs[h4 + 2][rw] = v.z; Qs[h4 + 3][rw] = v.w;
            }
        }
        __syncthreads();

        float acc[4][4] = {};
        #pragma unroll 4
        for (int h = 0; h < DIM; ++h) {
            float4 a  = *(const float4*)&Qs[h][ty * 4];
            float4 kv = *(const float4*)&Kt[h][tx * 4];
            float av[4] = {a.x, a.y, a.z, a.w};
            float bv[4] = {kv.x, kv.y, kv.z, kv.w};
            #pragma unroll
            for (int i = 0; i < 4; ++i)
                #pragma unroll
                for (int j = 0; j < 4; ++j)
                    acc[i][j] += av[i] * bv[j];
        }

        // tile column max
        #pragma unroll
        for (int j = 0; j < 4; ++j) {
            float t = fmaxf(fmaxf(acc[0][j], acc[1][j]), fmaxf(acc[2][j], acc[3][j]));
            red[ty][tx * 4 + j] = t;
        }
        __syncthreads();
        if (tid < 64) {
            float mt = red[0][tid];
            #pragma unroll
            for (int t = 1; t < 16; ++t) mt = fmaxf(mt, red[t][tid]);
            float m_old = colm[tid];
            float m_new = fmaxf(m_old, mt);
            coll[tid] *= __expf(m_old - m_new);
            colm[tid] = m_new;
        }
        __syncthreads();

        // tile column sum of exp
        #pragma unroll
        for (int j = 0; j < 4; ++j) {
            float mj = colm[tx * 4 + j];
            float s = __expf(acc[0][j] - mj) + __expf(acc[1][j] - mj) +
                      __expf(acc[2][j] - mj) + __expf(acc[3][j] - mj);
            red[ty][tx * 4 + j] = s;
        }
        __syncthreads();
        if (tid < 64) {
            float s = 0.f;
            #pragma unroll
            for (int t = 0; t < 16; ++t) s += red[t][tid];
            coll[tid] += s;
        }
        __syncthreads();
    }

    if (tid < 64) {
        mb[(size_t)b * SEQ + kt * 64 + tid] = colm[tid];
        lb[(size_t)b * SEQ + kt * 64 + tid] = coll[tid];
    }
}

// ---------------------------------------------------------------------------
// Kernel 3: out[b,q] = bf + sum_k exp(s[q,k]-m[k]) * (vf[k]/l[k])
// Block owns (b, 64 q-rows); iterates k-tiles.
// ---------------------------------------------------------------------------
__global__ __launch_bounds__(256) void k_out(
    const float* __restrict__ Qb, const float* __restrict__ Kb,
    const float* __restrict__ mb, const float* __restrict__ lb,
    const float* __restrict__ vf, const float* __restrict__ bfp,
    float* __restrict__ outp)
{
    const int b  = blockIdx.y;
    const int qt = blockIdx.x;
    __shared__ float Qs[DIM][64];
    __shared__ float Kt[DIM][64];
    __shared__ float mcol[64], wcol[64];
    __shared__ float red[64][16];

    const int tid = threadIdx.x;
    const int ty = tid >> 4, tx = tid & 15;

    // stage block's Q tile once (transposed)
    {
        const float4* Qb4 = (const float4*)(Qb + ((size_t)b * SEQ + qt * 64) * DIM);
        for (int i = tid; i < 64 * 16; i += 256) {
            int rw = i >> 4;
            int h4 = (i & 15) << 2;
            float4 v = Qb4[i];
            Qs[h4 + 0][rw] = v.x; Qs[h4 + 1][rw] = v.y;
            Qs[h4 + 2][rw] = v.z; Qs[h4 + 3][rw] = v.w;
        }
    }

    float rowsum[4] = {0.f, 0.f, 0.f, 0.f};

    for (int ktile = 0; ktile < SEQ / 64; ++ktile) {
        {
            const float4* Kb4 = (const float4*)(Kb + ((size_t)b * SEQ + ktile * 64) * DIM);
            for (int i = tid; i < 64 * 16; i += 256) {
                int rw = i >> 4;
                int h4 = (i & 15) << 2;
                float4 v = Kb4[i];
                Kt[h4 + 0][rw] = v.x; Kt[h4 + 1][rw] = v.y;
                Kt[h4 + 2][rw] = v.z; Kt[h4 + 3][rw] = v.w;
            }
        }
        if (tid < 64) {
            size_t col = (size_t)b * SEQ + ktile * 64 + tid;
            mcol[tid] = mb[col];
            wcol[tid] = vf[col] / lb[col];
        }
        __syncthreads();

        float acc[4][4] = {};
        #pragma unroll 4
        for (int h = 0; h < DIM; ++h) {
            float4 a  = *(const float4*)&Qs[h][ty * 4];
            float4 kv = *(const float4*)&Kt[h][tx * 4];
            float av[4] = {a.x, a.y, a.z, a.w};
            float bv[4] = {kv.x, kv.y, kv.z, kv.w};
            #pragma unroll
            for (int i = 0; i < 4; ++i)
                #pragma unroll
                for (int j = 0; j < 4; ++j)
                    acc[i][j] += av[i] * bv[j];
        }

        #pragma unroll
        for (int j = 0; j < 4; ++j) {
            float mj = mcol[tx * 4 + j];
            float wj = wcol[tx * 4 + j];
            #pragma unroll
            for (int i = 0; i < 4; ++i)
                rowsum[i] += __expf(acc[i][j] - mj) * wj;
        }
        __syncthreads();
    }

    #pragma unroll
    for (int i = 0; i < 4; ++i) red[ty * 4 + i][tx] = rowsum[i];
    __syncthreads();
    if (tid < 64) {
        float s = bfp[0];
        #pragma unroll
        for (int t = 0; t < 16; ++t) s += red[tid][t];
        outp[(size_t)b * SEQ + qt * 64 + tid] = s;
    }
}

// ---------------------------------------------------------------------------
extern "C" void kernel_launch(void* const* d_in, const int* in_sizes, int n_in,
                              void* d_out, int out_size, void* d_ws, size_t ws_size,
                              hipStream_t stream) {
    (void)in_sizes; (void)n_in; (void)out_size; (void)ws_size;
    const float* x  = (const float*)d_in[0];
    const float* Wq = (const float*)d_in[1];
    const float* Wk = (const float*)d_in[2];
    const float* Wv = (const float*)d_in[3];
    const float* Wf = (const float*)d_in[4];
    const float* bf = (const float*)d_in[5];
    float* outp = (float*)d_out;

    float* wvf = (float*)d_ws;                    // 128 floats (pad to 256)
    float* Qb  = wvf + 256;                       // B*S*D
    float* Kb  = Qb + (size_t)BATCH * SEQ * DIM;  // B*S*D
    float* vf  = Kb + (size_t)BATCH * SEQ * DIM;  // B*S
    float* mb  = vf + (size_t)BATCH * SEQ;        // B*S
    float* lb  = mb + (size_t)BATCH * SEQ;        // B*S

    k_wvf<<<1, 128, 0, stream>>>(Wv, Wf, wvf);
    k_qkv<<<BATCH * SEQ / ROWS, 256, 0, stream>>>(x, Wq, Wk, wvf, Qb, Kb, vf);
    k_stats<<<dim3(SEQ / 64, BATCH), 256, 0, stream>>>(Qb, Kb, mb, lb);
    k_out<<<dim3(SEQ / 64, BATCH), 256, 0, stream>>>(Qb, Kb, mb, lb, vf, bf, outp);
}

// Round 2
// 169.353 us; speedup vs baseline: 2.6445x; 2.6445x over previous
//
#include <hip/hip_runtime.h>
#include <math.h>

#define BATCH 16
#define SEQ   2048
#define HID   128
#define DIM   64

typedef __attribute__((ext_vector_type(8))) short bf16x8;
typedef __attribute__((ext_vector_type(4))) float f32x4;

static __device__ __forceinline__ ushort f2bf(float f) {
    union { float f; unsigned u; } v; v.f = f;
    unsigned r = v.u + 0x7FFFu + ((v.u >> 16) & 1u);   // RNE
    return (ushort)(r >> 16);
}

// ---------------------------------------------------------------------------
// Kernel 0: wvf[h] = sum_d Wv[h][d] * Wf[d]
// ---------------------------------------------------------------------------
__global__ void k_wvf(const float* __restrict__ Wv, const float* __restrict__ Wf,
                      float* __restrict__ wvf) {
    int h = threadIdx.x;
    if (h < HID) {
        float s = 0.f;
        #pragma unroll 8
        for (int d = 0; d < DIM; ++d) s += Wv[h * DIM + d] * Wf[d];
        wvf[h] = s;
    }
}

// ---------------------------------------------------------------------------
// Kernel 1: xp = x + PE;  Q = xp@Wq/8 (bf16);  K = xp@Wk (bf16);  vf = xp@wvf
// fp32 compute, bf16 rounding only at the store (keeps score-GEMM inputs
// accurate to one rounding).
// ---------------------------------------------------------------------------
#define ROWS 16
__global__ __launch_bounds__(256) void k_qkv(
    const float* __restrict__ x, const float* __restrict__ Wq,
    const float* __restrict__ Wk, const float* __restrict__ wvf,
    ushort* __restrict__ Qb, ushort* __restrict__ Kb, float* __restrict__ vf)
{
    __shared__ float xs[ROWS][HID];
    __shared__ float wqs[HID * DIM];
    __shared__ float wks[HID * DIM];
    __shared__ float vred[ROWS][16];

    const int tid = threadIdx.x;

    {
        const float4* Wq4 = (const float4*)Wq;
        const float4* Wk4 = (const float4*)Wk;
        float4* wqs4 = (float4*)wqs;
        float4* wks4 = (float4*)wks;
        for (int i = tid; i < HID * DIM / 4; i += 256) {
            wqs4[i] = Wq4[i];
            wks4[i] = Wk4[i];
        }
    }

    {
        const float c0 = 9.2103403719761836f / 128.0f;  // ln(10000)/HID
        const float4* x4 = (const float4*)x;
        const int pos_base = (blockIdx.x & (SEQ / ROWS - 1)) * ROWS;
        for (int it = tid; it < ROWS * HID / 4; it += 256) {
            int r  = it >> 5;
            int h0 = (it & 31) << 2;
            float4 v = x4[(size_t)blockIdx.x * (ROWS * HID / 4) + it];
            float pos = (float)(pos_base + r);
            float vv[4] = {v.x, v.y, v.z, v.w};
            #pragma unroll
            for (int j = 0; j < 4; ++j) {
                int h = h0 + j;
                float ang = pos * __expf(-(float)(h & ~1) * c0);
                vv[j] += (h & 1) ? __cosf(ang) : __sinf(ang);
            }
            float4 o = {vv[0], vv[1], vv[2], vv[3]};
            *(float4*)&xs[r][h0] = o;
        }
    }
    __syncthreads();

    const int r = tid >> 4;
    const int c = tid & 15;

    float qa[4] = {0.f, 0.f, 0.f, 0.f};
    float ka[4] = {0.f, 0.f, 0.f, 0.f};
    #pragma unroll 4
    for (int h = 0; h < HID; ++h) {
        float xv = xs[r][h];
        float4 wq4 = *(const float4*)&wqs[h * DIM + c * 4];
        float4 wk4 = *(const float4*)&wks[h * DIM + c * 4];
        qa[0] += xv * wq4.x; qa[1] += xv * wq4.y; qa[2] += xv * wq4.z; qa[3] += xv * wq4.w;
        ka[0] += xv * wk4.x; ka[1] += xv * wk4.y; ka[2] += xv * wk4.z; ka[3] += xv * wk4.w;
    }

    const size_t row = (size_t)blockIdx.x * ROWS + r;
    const float qscale = 0.125f;  // 1/sqrt(64)
    ushort4 qo = {f2bf(qa[0] * qscale), f2bf(qa[1] * qscale),
                  f2bf(qa[2] * qscale), f2bf(qa[3] * qscale)};
    ushort4 ko = {f2bf(ka[0]), f2bf(ka[1]), f2bf(ka[2]), f2bf(ka[3])};
    *(ushort4*)&Qb[row * DIM + c * 4] = qo;
    *(ushort4*)&Kb[row * DIM + c * 4] = ko;

    float p = 0.f;
    #pragma unroll
    for (int j = 0; j < 8; ++j) p += xs[r][c * 8 + j] * wvf[c * 8 + j];
    vred[r][c] = p;
    __syncthreads();
    if (c == 0) {
        float s = 0.f;
        #pragma unroll
        for (int j = 0; j < 16; ++j) s += vred[r][j];
        vf[row] = s;
    }
}

// ---------------------------------------------------------------------------
// Kernel 2 (MFMA): column stats over q for 32 k-cols per block.
// 4 waves split q into quarters; online (m,l) per column; LDS merge.
// Writes mb (col max) and wb = vf / l.
// A/B frag: lane holds row (lane&15), d = quad*8 + j (+32 per chunk).
// C/D: col = lane&15, row = quad*4 + reg.
// ---------------------------------------------------------------------------
__global__ __launch_bounds__(256) void k_stats(
    const ushort* __restrict__ Qb, const ushort* __restrict__ Kb,
    const float* __restrict__ vf, float* __restrict__ mb, float* __restrict__ wb)
{
    const int b    = blockIdx.y;
    const int k0   = blockIdx.x * 32;
    const int tid  = threadIdx.x;
    const int wave = tid >> 6;
    const int lane = tid & 63;
    const int quad = lane >> 4;
    const int col  = lane & 15;

    __shared__ float sm[4][32], sl[4][32];

    // resident K fragments: 2 tiles x 2 chunks
    bf16x8 kf[2][2];
    {
        const ushort* Kbase = Kb + ((size_t)(b * SEQ + k0)) * DIM;
        #pragma unroll
        for (int t = 0; t < 2; ++t)
            #pragma unroll
            for (int c = 0; c < 2; ++c)
                kf[t][c] = *(const bf16x8*)(Kbase + (size_t)(t * 16 + col) * DIM + quad * 8 + c * 32);
    }

    float m0 = -3.0e38f, m1 = -3.0e38f;
    float l0 = 0.f, l1 = 0.f;

    const ushort* Qrow = Qb + ((size_t)(b * SEQ + wave * 512 + col)) * DIM + quad * 8;

    for (int qi = 0; qi < 32; ++qi) {
        bf16x8 a0 = *(const bf16x8*)(Qrow);
        bf16x8 a1 = *(const bf16x8*)(Qrow + 32);
        Qrow += 16 * DIM;

        f32x4 acc0 = {0.f, 0.f, 0.f, 0.f};
        f32x4 acc1 = {0.f, 0.f, 0.f, 0.f};
        acc0 = __builtin_amdgcn_mfma_f32_16x16x32_bf16(a0, kf[0][0], acc0, 0, 0, 0);
        acc0 = __builtin_amdgcn_mfma_f32_16x16x32_bf16(a1, kf[0][1], acc0, 0, 0, 0);
        acc1 = __builtin_amdgcn_mfma_f32_16x16x32_bf16(a0, kf[1][0], acc1, 0, 0, 0);
        acc1 = __builtin_amdgcn_mfma_f32_16x16x32_bf16(a1, kf[1][1], acc1, 0, 0, 0);

        // tile 0
        {
            float tm = fmaxf(fmaxf(acc0.x, acc0.y), fmaxf(acc0.z, acc0.w));
            tm = fmaxf(tm, __shfl_xor(tm, 16));
            tm = fmaxf(tm, __shfl_xor(tm, 32));
            float mn = fmaxf(m0, tm);
            l0 *= __expf(m0 - mn);
            m0 = mn;
            l0 += __expf(acc0.x - mn) + __expf(acc0.y - mn) +
                  __expf(acc0.z - mn) + __expf(acc0.w - mn);
        }
        // tile 1
        {
            float tm = fmaxf(fmaxf(acc1.x, acc1.y), fmaxf(acc1.z, acc1.w));
            tm = fmaxf(tm, __shfl_xor(tm, 16));
            tm = fmaxf(tm, __shfl_xor(tm, 32));
            float mn = fmaxf(m1, tm);
            l1 *= __expf(m1 - mn);
            m1 = mn;
            l1 += __expf(acc1.x - mn) + __expf(acc1.y - mn) +
                  __expf(acc1.z - mn) + __expf(acc1.w - mn);
        }
    }

    // sum l over the 4 quads (m already replicated per col)
    l0 += __shfl_xor(l0, 16); l0 += __shfl_xor(l0, 32);
    l1 += __shfl_xor(l1, 16); l1 += __shfl_xor(l1, 32);

    if (quad == 0) {
        sm[wave][col]      = m0;  sl[wave][col]      = l0;
        sm[wave][16 + col] = m1;  sl[wave][16 + col] = l1;
    }
    __syncthreads();

    if (tid < 32) {
        float mm = fmaxf(fmaxf(sm[0][tid], sm[1][tid]), fmaxf(sm[2][tid], sm[3][tid]));
        float ll = sl[0][tid] * __expf(sm[0][tid] - mm) +
                   sl[1][tid] * __expf(sm[1][tid] - mm) +
                   sl[2][tid] * __expf(sm[2][tid] - mm) +
                   sl[3][tid] * __expf(sm[3][tid] - mm);
        size_t g = (size_t)b * SEQ + k0 + tid;
        mb[g] = mm;
        wb[g] = vf[g] / ll;
    }
}

// ---------------------------------------------------------------------------
// Kernel 3 (MFMA): out[b,q] = bf + sum_k exp(s[q,k]-m[k]) * w[k]
// Block owns 32 q-rows; 4 waves split k into quarters; LDS merge.
// ---------------------------------------------------------------------------
__global__ __launch_bounds__(256) void k_out(
    const ushort* __restrict__ Qb, const ushort* __restrict__ Kb,
    const float* __restrict__ mb, const float* __restrict__ wb,
    const float* __restrict__ bfp, float* __restrict__ outp)
{
    const int b    = blockIdx.y;
    const int q0   = blockIdx.x * 32;
    const int tid  = threadIdx.x;
    const int wave = tid >> 6;
    const int lane = tid & 63;
    const int quad = lane >> 4;
    const int col  = lane & 15;

    __shared__ float sred[4][32];

    // resident Q fragments: 2 tiles x 2 chunks
    bf16x8 qf[2][2];
    {
        const ushort* Qbase = Qb + ((size_t)(b * SEQ + q0)) * DIM;
        #pragma unroll
        for (int t = 0; t < 2; ++t)
            #pragma unroll
            for (int c = 0; c < 2; ++c)
                qf[t][c] = *(const bf16x8*)(Qbase + (size_t)(t * 16 + col) * DIM + quad * 8 + c * 32);
    }

    float racc0[4] = {0.f, 0.f, 0.f, 0.f};
    float racc1[4] = {0.f, 0.f, 0.f, 0.f};

    const ushort* Krow = Kb + ((size_t)(b * SEQ + wave * 512 + col)) * DIM + quad * 8;
    const float*  mptr = mb + (size_t)b * SEQ + wave * 512 + col;
    const float*  wptr = wb + (size_t)b * SEQ + wave * 512 + col;

    for (int ki = 0; ki < 32; ++ki) {
        bf16x8 b0 = *(const bf16x8*)(Krow);
        bf16x8 b1 = *(const bf16x8*)(Krow + 32);
        Krow += 16 * DIM;
        float mc = *mptr; mptr += 16;
        float wc = *wptr; wptr += 16;

        f32x4 acc0 = {0.f, 0.f, 0.f, 0.f};
        f32x4 acc1 = {0.f, 0.f, 0.f, 0.f};
        acc0 = __builtin_amdgcn_mfma_f32_16x16x32_bf16(qf[0][0], b0, acc0, 0, 0, 0);
        acc0 = __builtin_amdgcn_mfma_f32_16x16x32_bf16(qf[0][1], b1, acc0, 0, 0, 0);
        acc1 = __builtin_amdgcn_mfma_f32_16x16x32_bf16(qf[1][0], b0, acc1, 0, 0, 0);
        acc1 = __builtin_amdgcn_mfma_f32_16x16x32_bf16(qf[1][1], b1, acc1, 0, 0, 0);

        racc0[0] += __expf(acc0.x - mc) * wc;
        racc0[1] += __expf(acc0.y - mc) * wc;
        racc0[2] += __expf(acc0.z - mc) * wc;
        racc0[3] += __expf(acc0.w - mc) * wc;
        racc1[0] += __expf(acc1.x - mc) * wc;
        racc1[1] += __expf(acc1.y - mc) * wc;
        racc1[2] += __expf(acc1.z - mc) * wc;
        racc1[3] += __expf(acc1.w - mc) * wc;
    }

    // sum across the 16 columns (low 4 lane bits)
    #pragma unroll
    for (int r = 0; r < 4; ++r) {
        float v = racc0[r];
        v += __shfl_xor(v, 1); v += __shfl_xor(v, 2);
        v += __shfl_xor(v, 4); v += __shfl_xor(v, 8);
        racc0[r] = v;
        v = racc1[r];
        v += __shfl_xor(v, 1); v += __shfl_xor(v, 2);
        v += __shfl_xor(v, 4); v += __shfl_xor(v, 8);
        racc1[r] = v;
    }

    if (col == 0) {
        #pragma unroll
        for (int r = 0; r < 4; ++r) {
            sred[wave][quad * 4 + r]      = racc0[r];
            sred[wave][16 + quad * 4 + r] = racc1[r];
        }
    }
    __syncthreads();

    if (tid < 32) {
        float s = bfp[0] + sred[0][tid] + sred[1][tid] + sred[2][tid] + sred[3][tid];
        outp[(size_t)b * SEQ + q0 + tid] = s;
    }
}

// ---------------------------------------------------------------------------
extern "C" void kernel_launch(void* const* d_in, const int* in_sizes, int n_in,
                              void* d_out, int out_size, void* d_ws, size_t ws_size,
                              hipStream_t stream) {
    (void)in_sizes; (void)n_in; (void)out_size; (void)ws_size;
    const float* x  = (const float*)d_in[0];
    const float* Wq = (const float*)d_in[1];
    const float* Wk = (const float*)d_in[2];
    const float* Wv = (const float*)d_in[3];
    const float* Wf = (const float*)d_in[4];
    const float* bf = (const float*)d_in[5];
    float* outp = (float*)d_out;

    float*  wvf = (float*)d_ws;                        // 256 floats
    ushort* Qb  = (ushort*)(wvf + 256);                // B*S*D bf16
    ushort* Kb  = Qb + (size_t)BATCH * SEQ * DIM;      // B*S*D bf16
    float*  vf  = (float*)(Kb + (size_t)BATCH * SEQ * DIM);
    float*  mb  = vf + (size_t)BATCH * SEQ;
    float*  wb  = mb + (size_t)BATCH * SEQ;

    k_wvf<<<1, 128, 0, stream>>>(Wv, Wf, wvf);
    k_qkv<<<BATCH * SEQ / ROWS, 256, 0, stream>>>(x, Wq, Wk, wvf, Qb, Kb, vf);
    k_stats<<<dim3(SEQ / 32, BATCH), 256, 0, stream>>>(Qb, Kb, vf, mb, wb);
    k_out<<<dim3(SEQ / 32, BATCH), 256, 0, stream>>>(Qb, Kb, mb, wb, bf, outp);
}

// Round 4
// 139.230 us; speedup vs baseline: 3.2167x; 1.2164x over previous
//
#include <hip/hip_runtime.h>
#include <math.h>

#define BATCH 16
#define SEQ   2048
#define HID   128
#define DIM   64

typedef __attribute__((ext_vector_type(8))) short bf16x8;
typedef __attribute__((ext_vector_type(4))) float f32x4;

// 0.125 (1/sqrt(D)) * log2(e): folded into Wq so MFMA emits log2-domain scores
#define QSCALE 0.18033688011112042f
#define C0_PE  0.07195578314043169f   // ln(10000)/128

static __device__ __forceinline__ ushort f2bf(float f) {
    union { float f; unsigned u; } v; v.f = f;
    unsigned r = v.u + 0x7FFFu + ((v.u >> 16) & 1u);   // RNE
    return (ushort)(r >> 16);
}

static __device__ __forceinline__ float fast_exp2(float x) {
#if __has_builtin(__builtin_amdgcn_exp2f)
    return __builtin_amdgcn_exp2f(x);
#else
    return exp2f(x);
#endif
}

// ---------------------------------------------------------------------------
// Prep: wvf[h] = Wv[h,:]·Wf  and  Wt[col][k] = bf16 of [Wq*QSCALE | Wk]^T
// ---------------------------------------------------------------------------
__global__ void k_prep(const float* __restrict__ Wq, const float* __restrict__ Wk,
                       const float* __restrict__ Wv, const float* __restrict__ Wf,
                       ushort* __restrict__ Wt, float* __restrict__ wvf) {
    const int tid = threadIdx.x;
    if (tid < HID) {
        float s = 0.f;
        #pragma unroll 8
        for (int d = 0; d < DIM; ++d) s += Wv[tid * DIM + d] * Wf[d];
        wvf[tid] = s;
    }
    for (int i = tid; i < 128 * 128; i += 256) {
        int col = i >> 7, k = i & 127;
        float v = (col < 64) ? Wq[k * DIM + col] * QSCALE : Wk[k * DIM + (col - 64)];
        Wt[i] = f2bf(v);
    }
}

// ---------------------------------------------------------------------------
// QKV (MFMA, no LDS): block = 64 rows, wave = 16 rows.
// Each lane builds its A-fragment of xp = x + PE straight from global x,
// then sweeps 8 column tiles of Wt (4 Q tiles pre-scaled, 4 K tiles).
// Also vf[row] = xp_fp32 · wvf via quad shuffle reduce.
// ---------------------------------------------------------------------------
__global__ __launch_bounds__(256) void k_qkv(
    const float* __restrict__ x, const ushort* __restrict__ Wt,
    const float* __restrict__ wvf, ushort* __restrict__ Qb,
    ushort* __restrict__ Kb, float* __restrict__ vf)
{
    const int tid  = threadIdx.x;
    const int wave = tid >> 6;
    const int lane = tid & 63;
    const int quad = lane >> 4;
    const int col  = lane & 15;
    const int rowbase = blockIdx.x * 64 + wave * 16;
    const int grow = rowbase + col;          // this lane's xp row (A m-index)
    const float pos = (float)(grow & (SEQ - 1));

    // ---- build A fragments (4 chunks of k=32) + vf partial ----
    bf16x8 af[4];
    float vpart = 0.f;
    #pragma unroll
    for (int c = 0; c < 4; ++c) {
        const float* xp = x + (size_t)grow * HID + quad * 8 + c * 32;
        float4 v0 = *(const float4*)(xp);
        float4 v1 = *(const float4*)(xp + 4);
        float t[8] = {v0.x, v0.y, v0.z, v0.w, v1.x, v1.y, v1.z, v1.w};
        #pragma unroll
        for (int jp = 0; jp < 4; ++jp) {
            int h = quad * 8 + c * 32 + jp * 2;      // even
            float ang = pos * __expf(-(float)h * C0_PE);
            t[jp * 2]     += __sinf(ang);
            t[jp * 2 + 1] += __cosf(ang);
        }
        const float* wp = wvf + quad * 8 + c * 32;
        float4 w0 = *(const float4*)(wp);
        float4 w1 = *(const float4*)(wp + 4);
        vpart += t[0] * w0.x + t[1] * w0.y + t[2] * w0.z + t[3] * w0.w +
                 t[4] * w1.x + t[5] * w1.y + t[6] * w1.z + t[7] * w1.w;
        short* ap = (short*)&af[c];
        #pragma unroll
        for (int j = 0; j < 8; ++j) ap[j] = (short)f2bf(t[j]);
    }

    vpart += __shfl_xor(vpart, 16);
    vpart += __shfl_xor(vpart, 32);
    if (quad == 0) vf[grow] = vpart;

    // ---- 8 col tiles: 0..3 -> Q (prescaled), 4..7 -> K ----
    #pragma unroll
    for (int t = 0; t < 8; ++t) {
        const ushort* wrow = Wt + (size_t)(t * 16 + col) * 128 + quad * 8;
        f32x4 acc = {0.f, 0.f, 0.f, 0.f};
        #pragma unroll
        for (int c = 0; c < 4; ++c) {
            bf16x8 bfr = *(const bf16x8*)(wrow + c * 32);
            acc = __builtin_amdgcn_mfma_f32_16x16x32_bf16(af[c], bfr, acc, 0, 0, 0);
        }
        // C layout: col = lane&15, row = quad*4 + r
        const int cb = (t & 3) * 16 + col;
        ushort* dst = (t < 4) ? Qb : Kb;
        const int r0 = rowbase + quad * 4;
        #pragma unroll
        for (int r = 0; r < 4; ++r)
            dst[(size_t)(r0 + r) * DIM + cb] = f2bf(acc[r]);
    }
}

// ---------------------------------------------------------------------------
// Stats (MFMA): block = (b, 64 k-cols), 8 waves each sweep 256 q rows.
// No max: l[k] = sum_q exp2(s'[q,k])  (|s'| <= ~13, no overflow possible).
// Writes wb = vf / l only.
// ---------------------------------------------------------------------------
__global__ __launch_bounds__(512) void k_stats(
    const ushort* __restrict__ Qb, const ushort* __restrict__ Kb,
    const float* __restrict__ vf, float* __restrict__ wb)
{
    const int b    = blockIdx.y;
    const int k0   = blockIdx.x * 64;
    const int tid  = threadIdx.x;
    const int wave = tid >> 6;
    const int lane = tid & 63;
    const int quad = lane >> 4;
    const int col  = lane & 15;

    __shared__ float sl[8][64];

    bf16x8 kf[4][2];
    {
        const ushort* Kbase = Kb + ((size_t)(b * SEQ + k0)) * DIM;
        #pragma unroll
        for (int t = 0; t < 4; ++t)
            #pragma unroll
            for (int c = 0; c < 2; ++c)
                kf[t][c] = *(const bf16x8*)(Kbase + (size_t)(t * 16 + col) * DIM + quad * 8 + c * 32);
    }

    float l[4] = {0.f, 0.f, 0.f, 0.f};
    const ushort* Qrow = Qb + ((size_t)(b * SEQ + wave * 256 + col)) * DIM + quad * 8;

    for (int qi = 0; qi < 16; ++qi) {
        bf16x8 a0 = *(const bf16x8*)(Qrow);
        bf16x8 a1 = *(const bf16x8*)(Qrow + 32);
        Qrow += 16 * DIM;
        #pragma unroll
        for (int t = 0; t < 4; ++t) {
            f32x4 acc = {0.f, 0.f, 0.f, 0.f};
            acc = __builtin_amdgcn_mfma_f32_16x16x32_bf16(a0, kf[t][0], acc, 0, 0, 0);
            acc = __builtin_amdgcn_mfma_f32_16x16x32_bf16(a1, kf[t][1], acc, 0, 0, 0);
            l[t] += fast_exp2(acc.x) + fast_exp2(acc.y) +
                    fast_exp2(acc.z) + fast_exp2(acc.w);
        }
    }

    #pragma unroll
    for (int t = 0; t < 4; ++t) {
        l[t] += __shfl_xor(l[t], 16);
        l[t] += __shfl_xor(l[t], 32);
    }
    if (quad == 0) {
        #pragma unroll
        for (int t = 0; t < 4; ++t) sl[wave][t * 16 + col] = l[t];
    }
    __syncthreads();

    if (tid < 64) {
        float ll = 0.f;
        #pragma unroll
        for (int w = 0; w < 8; ++w) ll += sl[w][tid];
        size_t g = (size_t)b * SEQ + k0 + tid;
        wb[g] = vf[g] / ll;
    }
}

// ---------------------------------------------------------------------------
// Out (MFMA): block = (b, 64 q-rows), 8 waves each sweep 256 k cols.
// out[q] = bf + sum_k exp2(s'[q,k]) * w[k]
// ---------------------------------------------------------------------------
__global__ __launch_bounds__(512) void k_out(
    const ushort* __restrict__ Qb, const ushort* __restrict__ Kb,
    const float* __restrict__ wb, const float* __restrict__ bfp,
    float* __restrict__ outp)
{
    const int b    = blockIdx.y;
    const int q0   = blockIdx.x * 64;
    const int tid  = threadIdx.x;
    const int wave = tid >> 6;
    const int lane = tid & 63;
    const int quad = lane >> 4;
    const int col  = lane & 15;

    __shared__ float sred[8][64];

    bf16x8 qf[4][2];
    {
        const ushort* Qbase = Qb + ((size_t)(b * SEQ + q0)) * DIM;
        #pragma unroll
        for (int t = 0; t < 4; ++t)
            #pragma unroll
            for (int c = 0; c < 2; ++c)
                qf[t][c] = *(const bf16x8*)(Qbase + (size_t)(t * 16 + col) * DIM + quad * 8 + c * 32);
    }

    float rs[4][4] = {};
    const ushort* Krow = Kb + ((size_t)(b * SEQ + wave * 256 + col)) * DIM + quad * 8;
    const float*  wptr = wb + (size_t)b * SEQ + wave * 256 + col;

    for (int ki = 0; ki < 16; ++ki) {
        bf16x8 b0 = *(const bf16x8*)(Krow);
        bf16x8 b1 = *(const bf16x8*)(Krow + 32);
        Krow += 16 * DIM;
        float wc = *wptr; wptr += 16;
        #pragma unroll
        for (int t = 0; t < 4; ++t) {
            f32x4 acc = {0.f, 0.f, 0.f, 0.f};
            acc = __builtin_amdgcn_mfma_f32_16x16x32_bf16(qf[t][0], b0, acc, 0, 0, 0);
            acc = __builtin_amdgcn_mfma_f32_16x16x32_bf16(qf[t][1], b1, acc, 0, 0, 0);
            #pragma unroll
            for (int r = 0; r < 4; ++r)
                rs[t][r] += fast_exp2(acc[r]) * wc;
        }
    }

    // reduce over the 16 k-cols (low 4 lane bits)
    #pragma unroll
    for (int t = 0; t < 4; ++t)
        #pragma unroll
        for (int r = 0; r < 4; ++r) {
            float v = rs[t][r];
            v += __shfl_xor(v, 1); v += __shfl_xor(v, 2);
            v += __shfl_xor(v, 4); v += __shfl_xor(v, 8);
            rs[t][r] = v;
        }

    if (col == 0) {
        #pragma unroll
        for (int t = 0; t < 4; ++t)
            #pragma unroll
            for (int r = 0; r < 4; ++r)
                sred[wave][t * 16 + quad * 4 + r] = rs[t][r];
    }
    __syncthreads();

    if (tid < 64) {
        float s = bfp[0];
        #pragma unroll
        for (int w = 0; w < 8; ++w) s += sred[w][tid];
        outp[(size_t)b * SEQ + q0 + tid] = s;
    }
}

// ---------------------------------------------------------------------------
extern "C" void kernel_launch(void* const* d_in, const int* in_sizes, int n_in,
                              void* d_out, int out_size, void* d_ws, size_t ws_size,
                              hipStream_t stream) {
    (void)in_sizes; (void)n_in; (void)out_size; (void)ws_size;
    const float* x  = (const float*)d_in[0];
    const float* Wq = (const float*)d_in[1];
    const float* Wk = (const float*)d_in[2];
    const float* Wv = (const float*)d_in[3];
    const float* Wf = (const float*)d_in[4];
    const float* bf = (const float*)d_in[5];
    float* outp = (float*)d_out;

    float*  wvf = (float*)d_ws;                                  // 256 floats
    float*  vf  = wvf + 256;                                     // B*S
    float*  wb  = vf + (size_t)BATCH * SEQ;                      // B*S
    ushort* Wt  = (ushort*)(wb + (size_t)BATCH * SEQ);           // 128*128
    ushort* Qb  = Wt + 128 * 128;                                // B*S*D bf16
    ushort* Kb  = Qb + (size_t)BATCH * SEQ * DIM;                // B*S*D bf16

    k_prep<<<1, 256, 0, stream>>>(Wq, Wk, Wv, Wf, Wt, wvf);
    k_qkv<<<BATCH * SEQ / 64, 256, 0, stream>>>(x, Wt, wvf, Qb, Kb, vf);
    k_stats<<<dim3(SEQ / 64, BATCH), 512, 0, stream>>>(Qb, Kb, vf, wb);
    k_out<<<dim3(SEQ / 64, BATCH), 512, 0, stream>>>(Qb, Kb, wb, bf, outp);
}